// Round 5
// baseline (7666.056 us; speedup 1.0000x reference)
//
#include <hip/hip_runtime.h>
#include <cstdint>
#include <cstddef>

#define SEQ 256
#define BATCH 128
#define HID 1024
#define H3 3072
#define TCH 32                 // timesteps per chunk
#define NCH (SEQ/TCH)          // chunks per layer
#define CROWS (TCH*BATCH)      // 4096 rows per chunk GEMM

typedef __bf16 bf16x8 __attribute__((ext_vector_type(8)));
typedef float f32x4 __attribute__((ext_vector_type(4)));
typedef unsigned short ushort8 __attribute__((ext_vector_type(8)));
typedef unsigned long long u64x2 __attribute__((ext_vector_type(2)));

static __device__ __forceinline__ unsigned short f2bf(float f){
  unsigned int u = __float_as_uint(f);
  u += 0x7fffu + ((u >> 16) & 1u);
  return (unsigned short)(u >> 16);
}
static __device__ __forceinline__ float sigm(float x){
  return 1.0f / (1.0f + __expf(-x));
}
static __device__ __forceinline__ float tanh_(float x){
  x = fminf(15.0f, fmaxf(-15.0f, x));
  float e = __expf(2.0f * x);
  return (e - 1.0f) / (e + 1.0f);
}

// ---------------- prologue kernels ----------------

__global__ __launch_bounds__(256) void cvt_bf16(const float* __restrict__ in,
                                                unsigned short* __restrict__ out, int n4){
  int i = blockIdx.x * blockDim.x + threadIdx.x;
  int stride = gridDim.x * blockDim.x;
  for (; i < n4; i += stride){
    float4 v = reinterpret_cast<const float4*>(in)[i];
    ushort4 o = { f2bf(v.x), f2bf(v.y), f2bf(v.z), f2bf(v.w) };
    reinterpret_cast<ushort4*>(out)[i] = o;
  }
}

__global__ __launch_bounds__(256) void embed_gather(const int* __restrict__ src,
                                                    const float* __restrict__ embW,
                                                    unsigned short* __restrict__ x0){
  int bx = blockIdx.x;            // = s*BATCH + b
  int s = bx >> 7, b = bx & 127;
  int row = src[b * SEQ + s];
  float4 v = reinterpret_cast<const float4*>(embW + (size_t)row * HID)[threadIdx.x];
  ushort4 o = { f2bf(v.x), f2bf(v.y), f2bf(v.z), f2bf(v.w) };
  reinterpret_cast<ushort4*>(x0 + (size_t)bx * HID)[threadIdx.x] = o;
}

__global__ __launch_bounds__(256) void zero_u32(unsigned* __restrict__ p, int n){
  int i = blockIdx.x * blockDim.x + threadIdx.x;
  if (i < n) p[i] = 0u;
}

// ---------------- chunk GEMM: gi = A @ B^T, C stored COLUMN-major ----------------
#define BM 128
#define BN 128
#define BK 32
#define LDT 40

__global__ __launch_bounds__(256) void gemm_xw(
    const unsigned short* __restrict__ A,
    const unsigned short* __restrict__ B,
    float* __restrict__ C)
{
  __shared__ unsigned short As[2][BM][LDT];
  __shared__ unsigned short Bs[2][BN][LDT];
  int tid = threadIdx.x;
  int lane = tid & 63, wid = tid >> 6;
  int fr = lane & 15, kg = lane >> 4;
  int wr = wid >> 1, wc = wid & 1;
  int brow = blockIdx.x * BM;
  int bcol = blockIdx.y * BN;

  int r0 = tid >> 2;
  int r1 = 64 + (tid >> 2);
  int k8 = (tid & 3) * 8;

  const unsigned short* Ab = A + (size_t)brow * HID;
  const unsigned short* Bb = B + (size_t)bcol * HID;

  f32x4 acc[4][4] = {};
  ushort8 a0, a1, b0, b1;

  a0 = *(const ushort8*)(Ab + (size_t)r0 * HID + k8);
  a1 = *(const ushort8*)(Ab + (size_t)r1 * HID + k8);
  b0 = *(const ushort8*)(Bb + (size_t)r0 * HID + k8);
  b1 = *(const ushort8*)(Bb + (size_t)r1 * HID + k8);
  *(ushort8*)&As[0][r0][k8] = a0;
  *(ushort8*)&As[0][r1][k8] = a1;
  *(ushort8*)&Bs[0][r0][k8] = b0;
  *(ushort8*)&Bs[0][r1][k8] = b1;
  __syncthreads();

  for (int kt = 0; kt < HID / BK; ++kt){
    int cur = kt & 1;
    if (kt < HID / BK - 1){
      int ko = (kt + 1) * BK + k8;
      a0 = *(const ushort8*)(Ab + (size_t)r0 * HID + ko);
      a1 = *(const ushort8*)(Ab + (size_t)r1 * HID + ko);
      b0 = *(const ushort8*)(Bb + (size_t)r0 * HID + ko);
      b1 = *(const ushort8*)(Bb + (size_t)r1 * HID + ko);
    }
    bf16x8 af[4], bfr[4];
    #pragma unroll
    for (int m = 0; m < 4; ++m)
      af[m] = *(const bf16x8*)&As[cur][wr*64 + m*16 + fr][kg*8];
    #pragma unroll
    for (int n = 0; n < 4; ++n)
      bfr[n] = *(const bf16x8*)&Bs[cur][wc*64 + n*16 + fr][kg*8];
    #pragma unroll
    for (int m = 0; m < 4; ++m)
      #pragma unroll
      for (int n = 0; n < 4; ++n)
        acc[m][n] = __builtin_amdgcn_mfma_f32_16x16x32_bf16(af[m], bfr[n], acc[m][n], 0,0,0);
    if (kt < HID / BK - 1){
      int nxt = cur ^ 1;
      *(ushort8*)&As[nxt][r0][k8] = a0;
      *(ushort8*)&As[nxt][r1][k8] = a1;
      *(ushort8*)&Bs[nxt][r0][k8] = b0;
      *(ushort8*)&Bs[nxt][r1][k8] = b1;
      __syncthreads();
    }
  }

  #pragma unroll
  for (int m = 0; m < 4; ++m){
    int rowb = brow + wr*64 + m*16 + kg*4;
    #pragma unroll
    for (int n = 0; n < 4; ++n){
      int col = bcol + wc*64 + n*16 + fr;
      *(f32x4*)(C + (size_t)col * CROWS + rowb) = acc[m][n];
    }
  }
}

// ---------------- persistent GRU chunk kernel (barrier-free steps) ----------------
// grid 256 WGs x 128 thr (2 waves). blockIdx.x = rgp*64 + ct.
// Wave w handles 16 batch rows (rowslice rs = rgp*2+w), cols ct*16..+15, 3 gates,
// full K=1024. No reduction, no per-step __syncthreads, no RMW atomics.
// h exchange: relaxed agent-scope u64 atomics (LLC); per-producer flag words.
#define LDW 1032

__global__ __launch_bounds__(128) void gru_persist(
    const unsigned short* __restrict__ Whh,   // layer [3072][1024] bf16
    const float* __restrict__ bih,
    const float* __restrict__ bhh,
    const float* __restrict__ gi,             // [3072][CROWS] col-major chunk
    float* __restrict__ ys_out,               // layer1: d_out ys base; else null
    unsigned short* __restrict__ x_next,      // layer0: x1 chunk base; else null
    unsigned long long* __restrict__ hbA,     // bf16 h ping-pong (u64 granules)
    unsigned long long* __restrict__ hbB,
    float* __restrict__ hf32,                 // lane-private f32 h carry
    float* __restrict__ state_out,            // layer state slot
    int t0,
    unsigned* __restrict__ flags)             // [TCH][8][64] this launch
{
  __shared__ unsigned short Wlds[48 * LDW];   // 99 KB
  __shared__ unsigned short hvt[2][16][16];   // 1 KB (per-wave transpose buf)

  int tid = threadIdx.x;
  int lane = tid & 63, w = tid >> 6;
  int ct = blockIdx.x & 63, rgp = blockIdx.x >> 6;
  int c0 = ct * 16;
  int rs = rgp * 2 + w;            // 16-row slice id, 0..7
  int R0 = rs * 16;                // base batch row
  int fr = lane & 15, kg = lane >> 4;

  // stage 48x1024 weight slice once per launch (both waves)
  #pragma unroll
  for (int j = 0; j < 48; ++j){
    int cid = j * 128 + tid;                  // 0..6143 chunks of 8 elems
    int r = cid >> 7, k8 = (cid & 127) * 8;
    int grow = (r >> 4) * HID + c0 + (r & 15);
    *(ushort8*)&Wlds[r * LDW + k8] = *(const ushort8*)(Whh + (size_t)grow * HID + k8);
  }

  int col = c0 + fr;
  float br_ = bih[col] + bhh[col];
  float bz_ = bih[HID + col] + bhh[HID + col];
  float bi_ = bih[2*HID + col];
  float bh_ = bhh[2*HID + col];

  // lane-private f32 h carry (rows R0+kg*4+q, col)
  float* hf_lane = hf32 + (((size_t)blockIdx.x * 2 + w) * 64 + lane) * 4;
  f32x4 hprev = {0,0,0,0};
  if (t0 > 0) hprev = *(const f32x4*)hf_lane;

  // gi base for this lane's 4 cells (col-major: rows contiguous)
  const float* gib = gi + (size_t)col * CROWS + R0 + kg * 4;
  const size_t GOFF = (size_t)HID * CROWS;

  __syncthreads();   // weights staged (the ONLY barrier besides this point)

  f32x4 g_r = *(const f32x4*)(gib);
  f32x4 g_z = *(const f32x4*)(gib + GOFF);
  f32x4 g_n = *(const f32x4*)(gib + 2*GOFF);

  for (int s = 0; s < TCH; ++s){
    int t = t0 + s;

    if (s > 0){
      const unsigned* fp = flags + ((s - 1) * 8 + rs) * 64;
      int lim = 2000000;
      for (;;){
        unsigned f = __hip_atomic_load(fp + lane, __ATOMIC_RELAXED, __HIP_MEMORY_SCOPE_AGENT);
        if (__all(f != 0) || !--lim) break;
        __builtin_amdgcn_s_sleep(1);
      }
    }

    // prefetch next step's gi (consumed next iteration)
    f32x4 ngr = {0,0,0,0}, ngz = {0,0,0,0}, ngn = {0,0,0,0};
    if (s + 1 < TCH){
      const float* gp = gib + (size_t)(s + 1) * BATCH;
      ngr = *(const f32x4*)(gp);
      ngz = *(const f32x4*)(gp + GOFF);
      ngn = *(const f32x4*)(gp + 2*GOFF);
    }

    f32x4 accr = {0,0,0,0}, accz = {0,0,0,0}, accn = {0,0,0,0};
    if (t > 0){
      const unsigned long long* hin = (t & 1) ? hbB : hbA;
      const size_t abase = ((size_t)(R0 + fr) * HID + kg * 8) >> 2;
      #pragma unroll 8
      for (int ks = 0; ks < 32; ++ks){
        size_t ai = abase + ks * 8;           // 32 elems = 8 u64 per kstep
        unsigned long long u0 = __hip_atomic_load(hin + ai,     __ATOMIC_RELAXED, __HIP_MEMORY_SCOPE_AGENT);
        unsigned long long u1 = __hip_atomic_load(hin + ai + 1, __ATOMIC_RELAXED, __HIP_MEMORY_SCOPE_AGENT);
        u64x2 uu; uu[0] = u0; uu[1] = u1;
        bf16x8 a = __builtin_bit_cast(bf16x8, uu);
        int bo = ks * 32 + kg * 8;
        bf16x8 b0 = *(const bf16x8*)&Wlds[(     fr) * LDW + bo];
        bf16x8 b1 = *(const bf16x8*)&Wlds[(16 + fr) * LDW + bo];
        bf16x8 b2 = *(const bf16x8*)&Wlds[(32 + fr) * LDW + bo];
        accr = __builtin_amdgcn_mfma_f32_16x16x32_bf16(a, b0, accr, 0,0,0);
        accz = __builtin_amdgcn_mfma_f32_16x16x32_bf16(a, b1, accz, 0,0,0);
        accn = __builtin_amdgcn_mfma_f32_16x16x32_bf16(a, b2, accn, 0,0,0);
      }
    }

    // epilogue: this lane's 4 cells (col, rows R0+kg*4+q)
    f32x4 hnew;
    #pragma unroll
    for (int q = 0; q < 4; ++q){
      float rg_ = sigm(g_r[q] + accr[q] + br_);
      float zg  = sigm(g_z[q] + accz[q] + bz_);
      float ng  = tanh_(g_n[q] + bi_ + rg_ * (accn[q] + bh_));
      hnew[q] = (1.0f - zg) * ng + zg * hprev[q];
    }
    hprev = hnew;

    int rowq = R0 + kg * 4;
    if (ys_out){
      #pragma unroll
      for (int q = 0; q < 4; ++q)
        ys_out[((size_t)t * BATCH + rowq + q) * HID + col] = hnew[q];
    }
    if (x_next){
      #pragma unroll
      for (int q = 0; q < 4; ++q)
        x_next[((size_t)s * BATCH + rowq + q) * HID + col] = f2bf(hnew[q]);
    }
    if (t == SEQ - 1){
      #pragma unroll
      for (int q = 0; q < 4; ++q)
        state_out[(size_t)(rowq + q) * HID + col] = hnew[q];
    }
    if (s == TCH - 1)
      *(f32x4*)hf_lane = hprev;

    // publish bf16 h: per-wave LDS transpose, then 32 lanes store u64 atomics
    unsigned long long* hout = (t & 1) ? hbA : hbB;
    #pragma unroll
    for (int q = 0; q < 4; ++q)
      hvt[w][kg*4 + q][fr] = f2bf(hnew[q]);
    asm volatile("s_waitcnt lgkmcnt(0)" ::: "memory");
    if (lane < 32){
      int rr = lane >> 1, cc8 = (lane & 1) * 8;
      const unsigned long long* hp = (const unsigned long long*)&hvt[w][rr][cc8];
      size_t ui = ((size_t)(R0 + rr) * HID + c0 + cc8) >> 2;
      __hip_atomic_store(hout + ui,     hp[0], __ATOMIC_RELAXED, __HIP_MEMORY_SCOPE_AGENT);
      __hip_atomic_store(hout + ui + 1, hp[1], __ATOMIC_RELAXED, __HIP_MEMORY_SCOPE_AGENT);
    }
    asm volatile("s_waitcnt vmcnt(0)" ::: "memory");
    if (lane == 0)
      __hip_atomic_store(flags + (s * 8 + rs) * 64 + ct, 1u,
                         __ATOMIC_RELAXED, __HIP_MEMORY_SCOPE_AGENT);

    g_r = ngr; g_z = ngz; g_n = ngn;
  }
}

// ---------------- launch ----------------

extern "C" void kernel_launch(void* const* d_in, const int* in_sizes, int n_in,
                              void* d_out, int out_size, void* d_ws, size_t ws_size,
                              hipStream_t stream){
  (void)in_sizes; (void)n_in; (void)out_size; (void)ws_size;
  const int*   src  = (const int*)  d_in[0];
  const float* embW = (const float*)d_in[1];
  const float* Wih  = (const float*)d_in[2];
  const float* Whh  = (const float*)d_in[3];
  const float* bih  = (const float*)d_in[4];
  const float* bhh  = (const float*)d_in[5];
  float* out = (float*)d_out;

  char* ws = (char*)d_ws;
  size_t off = 0;
  auto carve = [&](size_t bytes) -> void* {
    void* p = ws + off;
    off += (bytes + 255) & ~(size_t)255;
    return p;
  };
  const size_t WELEM = (size_t)2 * H3 * HID;
  const int NFLAG = 2 * NCH * TCH * 8 * 64;    // u32 flags, all launches
  unsigned short* wihb = (unsigned short*)carve(WELEM * 2);
  unsigned short* whhb = (unsigned short*)carve(WELEM * 2);
  unsigned short* x0   = (unsigned short*)carve((size_t)SEQ*BATCH*HID*2);
  unsigned short* x1   = (unsigned short*)carve((size_t)SEQ*BATCH*HID*2);
  float*          gi   = (float*)         carve((size_t)CROWS*H3*4);
  unsigned long long* hbA = (unsigned long long*)carve((size_t)BATCH*HID*2);
  unsigned long long* hbB = (unsigned long long*)carve((size_t)BATCH*HID*2);
  float*          hf32 = (float*)         carve((size_t)512*64*4*4);
  unsigned*       flags= (unsigned*)      carve((size_t)NFLAG * 4);

  cvt_bf16<<<2048, 256, 0, stream>>>(Wih, wihb, (int)(WELEM/4));
  cvt_bf16<<<2048, 256, 0, stream>>>(Whh, whhb, (int)(WELEM/4));
  embed_gather<<<SEQ*BATCH, 256, 0, stream>>>(src, embW, x0);
  zero_u32<<<(NFLAG + 255)/256, 256, 0, stream>>>(flags, NFLAG);

  float* state = out + (size_t)SEQ*BATCH*HID;
  for (int l = 0; l < 2; ++l){
    const float* bihl = bih + l*H3;
    const float* bhhl = bhh + l*H3;
    const unsigned short* wl = wihb + (size_t)l*H3*HID;
    const unsigned short* vl = whhb + (size_t)l*H3*HID;
    for (int cch = 0; cch < NCH; ++cch){
      const unsigned short* Achunk = (l == 0) ? (x0 + (size_t)cch*CROWS*HID)
                                              : (x1 + (size_t)cch*CROWS*HID);
      gemm_xw<<<dim3(CROWS/BM, H3/BN), 256, 0, stream>>>(Achunk, wl, gi);
      int launch_id = l*NCH + cch;
      gru_persist<<<256, 128, 0, stream>>>(
          vl, bihl, bhhl, gi,
          (l == 1) ? out : nullptr,
          (l == 0) ? (x1 + (size_t)cch*CROWS*HID) : nullptr,
          hbA, hbB, hf32,
          state + (size_t)l*BATCH*HID,
          cch*TCH,
          flags + (size_t)launch_id * TCH * 8 * 64);
    }
  }
}